// Round 15
// baseline (645.136 us; speedup 1.0000x reference)
//
#include <hip/hip_runtime.h>

typedef _Float16 f16;
typedef __attribute__((ext_vector_type(8))) _Float16 f16x8;
typedef __attribute__((ext_vector_type(16))) float f32x16;

#define T_LEN 320
#define NGATE_BLOCKS 1024

// ---------------------------------------------------------------------------
// f16 two-limb split with scaled low limb (RNE): v = h + l/4096, res ~2^-24|v|
// ---------------------------------------------------------------------------
__device__ __forceinline__ void split2h(float v, unsigned short &h, unsigned short &l) {
    f16 hh = (f16)v;
    f16 ll = (f16)((v - (float)hh) * 4096.0f);
    h = __builtin_bit_cast(unsigned short, hh);
    l = __builtin_bit_cast(unsigned short, ll);
}

__device__ __forceinline__ void loadxg18(float* d, const float* __restrict__ p) {
#pragma unroll
    for (int q = 0; q < 9; ++q) {
        float2 v = *reinterpret_cast<const float2*>(p + q * 2);
        d[q * 2]     = v.x;
        d[q * 2 + 1] = v.y;
    }
}

// ---------------------------------------------------------------------------
// Prep kernel: weights -> 32x32x16 MFMA B-fragment layout (f16 limb pairs)
// ---------------------------------------------------------------------------
__global__ __launch_bounds__(256) void geo_prep_kernel(
    const float* __restrict__ k1, const float* __restrict__ c1b,
    const float* __restrict__ bn1s, const float* __restrict__ bn1b,
    const float* __restrict__ bn1m, const float* __restrict__ bn1v,
    const float* __restrict__ k2, const float* __restrict__ c2b,
    const float* __restrict__ bn2s, const float* __restrict__ bn2b,
    const float* __restrict__ bn2m, const float* __restrict__ bn2v,
    unsigned short* __restrict__ w1f, unsigned short* __restrict__ w2f,
    float* __restrict__ sb)
{
    const int tid = threadIdx.x;
    for (int e = tid; e < 20 * 64; e += 256) {
        const int ks = e >> 6, l = e & 63;
        const int lh = l >> 5, n = l & 31;
        for (int j = 0; j < 8; ++j) {
            const int kg = ks * 16 + lh * 8 + j;       // kg = w*64+ci
            unsigned short h, lo; split2h(k1[kg * 32 + n], h, lo);
            w1f[((ks * 2 + 0) * 64 + l) * 8 + j] = h;
            w1f[((ks * 2 + 1) * 64 + l) * 8 + j] = lo;
        }
    }
    for (int e = tid; e < 6 * 64; e += 256) {
        const int ks = e >> 6, l = e & 63;
        const int lh = l >> 5, n = l & 31;
        for (int j = 0; j < 8; ++j) {
            const int kg = ks * 16 + lh * 8 + j;       // kg = tap*32+ci2
            const float v = (n < 16) ? k2[kg * 16 + n] : 0.0f;
            unsigned short h, lo; split2h(v, h, lo);
            w2f[((ks * 2 + 0) * 64 + l) * 8 + j] = h;
            w2f[((ks * 2 + 1) * 64 + l) * 8 + j] = lo;
        }
    }
    if (tid < 32) {
        const float s1 = bn1s[tid] * (1.0f / sqrtf(bn1v[tid] + 1e-5f));
        sb[tid]      = s1;
        sb[32 + tid] = bn1b[tid] + (c1b[tid] - bn1m[tid]) * s1;
    }
    if (tid < 16) {
        const float s2 = bn2s[tid] * (1.0f / sqrtf(bn2v[tid] + 1e-5f));
        sb[64 + tid] = s2;
        sb[80 + tid] = bn2b[tid] + (c2b[tid] - bn2m[tid]) * s2;
    }
}

// ---------------------------------------------------------------------------
// Conv kernel (R10-verbatim conv path) + appended gate blocks.
//   blockIdx < ngate : gate role — 4 rows, compute sigmoid gate -> g_ws (B,16,T)
//   else             : conv role — block = (row, 64-t chunk), 20480 blocks
// ---------------------------------------------------------------------------
struct ConvSmem {
    unsigned short xh[70][64], xl[70][64];   // x slab, swizzled      17.9 KB
    unsigned short c1h[66][40], c1l[66][40]; // c1 slab (pad 40)      10.6 KB
};

#define MFMA32(A, B, C) __builtin_amdgcn_mfma_f32_32x32x16_f16((A), (B), (C), 0, 0, 0)

__global__ __launch_bounds__(256, 5) void geo_alif_conv_kernel(
    const float* __restrict__ x_eeg,
    const unsigned short* __restrict__ w1f, const unsigned short* __restrict__ w2f,
    const float* __restrict__ sb, float* __restrict__ e_ws,
    const float* __restrict__ x_geo, const float* __restrict__ geoW,
    const float* __restrict__ geob, float* __restrict__ g_ws, int ngate)
{
    __shared__ ConvSmem sm;
    __shared__ float gWs[19][16];
    const int tid = threadIdx.x, lane = tid & 63, wv = tid >> 6;
    const int l31 = lane & 31, lh = lane >> 5;

    if (blockIdx.x < (unsigned)ngate) {
        // ---------------- gate role: 4 rows, all T ----------------
        for (int i = tid; i < 288; i += 256) gWs[i / 16][i & 15] = geoW[i];
        if (tid < 16) gWs[18][tid] = geob[tid];
        __syncthreads();
        for (int task = wv; task < 20; task += 4) {        // 4 rows x 5 t-segs
            const int rr = task / 5, seg = task - rr * 5;
            const size_t gr = (size_t)blockIdx.x * 4 + rr;
            const int t = seg * 64 + lane;
            float xv[18];
            loadxg18(xv, x_geo + (gr * T_LEN + t) * 18);
#pragma unroll
            for (int hh = 0; hh < 16; ++hh) {
                float a = gWs[18][hh];
#pragma unroll
                for (int i = 0; i < 18; ++i) a = fmaf(xv[i], gWs[i][hh], a);
                g_ws[(gr * 16 + hh) * T_LEN + t] = 1.f / (1.f + expf(-a));
            }
        }
        return;
    }

    // ---------------- conv role (R10-verbatim) ----------------
    const int bid = blockIdx.x - ngate;
    const int row = bid / 5, cc = bid % 5;
    const int t0 = cc * 64;
    const float* xrow = x_eeg + (size_t)row * (T_LEN * 64);
    float* erow = e_ws + (size_t)row * (16 * T_LEN);

    // ---- stage x slab: 70 rows x 16 float4 groups, batched (5/thread) ----
    {
        float4 v[5];
#pragma unroll
        for (int q = 0; q < 5; ++q) {
            const int fi = tid + q * 256;
            float4 tv = {0.f, 0.f, 0.f, 0.f};
            if (fi < 1120) {
                const int s = fi >> 4;
                const int tabs = t0 - 3 + s;
                if (tabs >= 0 && tabs < T_LEN)
                    tv = *reinterpret_cast<const float4*>(xrow + (size_t)tabs * 64 + (fi & 15) * 4);
            }
            v[q] = tv;
        }
#pragma unroll
        for (int q = 0; q < 5; ++q) {
            const int fi = tid + q * 256;
            if (fi < 1120) {
                const int s = fi >> 4, cq = fi & 15;
                unsigned short h0,l0,h1,l1,h2,l2,h3,l3;
                split2h(v[q].x, h0, l0); split2h(v[q].y, h1, l1);
                split2h(v[q].z, h2, l2); split2h(v[q].w, h3, l3);
                const int off = (((cq >> 1) ^ (s & 7)) * 8) + (cq & 1) * 4;
                ushort4 hv = {h0, h1, h2, h3}, lv = {l0, l1, l2, l3};
                *reinterpret_cast<ushort4*>(&sm.xh[s][off]) = hv;
                *reinterpret_cast<ushort4*>(&sm.xl[s][off]) = lv;
            }
        }
    }
    __syncthreads();   // B1

    if (wv < 3) {
        // ---- conv1: frag = wv (output rows frag*32 .. +31; valid rl<66) ----
        const int frag = wv;
        const float s1 = sb[l31], b1 = sb[32 + l31];
        const f16x8* w1v = reinterpret_cast<const f16x8*>(w1f);
        f32x16 am, cx;
#pragma unroll
        for (int q = 0; q < 16; ++q) { am[q] = 0.f; cx[q] = 0.f; }
        f16x8 pbh[4], pbl[4], pah[3], pal[3];
#pragma unroll
        for (int p = 0; p < 4; ++p) {
            pbh[p] = w1v[(p * 2 + 0) * 64 + lane];
            pbl[p] = w1v[(p * 2 + 1) * 64 + lane];
        }
#pragma unroll
        for (int p = 0; p < 3; ++p) {
            const int kb = p * 16 + lh * 8;
            int s = frag * 32 + l31 + (kb >> 6); if (s > 69) s = 69;
            const int off = ((((kb & 63) >> 3) ^ (s & 7)) * 8);
            pah[p] = *reinterpret_cast<const f16x8*>(&sm.xh[s][off]);
            pal[p] = *reinterpret_cast<const f16x8*>(&sm.xl[s][off]);
        }
#pragma unroll
        for (int ks = 0; ks < 20; ++ks) {
            const f16x8 ah = pah[ks % 3], al = pal[ks % 3];
            const f16x8 bh = pbh[ks % 4], bl = pbl[ks % 4];
            am = MFMA32(ah, bh, am);
            cx = MFMA32(ah, bl, cx);
            cx = MFMA32(al, bh, cx);
            if (ks < 17) {
                const int kb = (ks + 3) * 16 + lh * 8;
                int s = frag * 32 + l31 + (kb >> 6); if (s > 69) s = 69;
                const int off = ((((kb & 63) >> 3) ^ (s & 7)) * 8);
                pah[ks % 3] = *reinterpret_cast<const f16x8*>(&sm.xh[s][off]);
                pal[ks % 3] = *reinterpret_cast<const f16x8*>(&sm.xl[s][off]);
            }
            if (ks < 16) {
                pbh[ks % 4] = w1v[((ks + 4) * 2 + 0) * 64 + lane];
                pbl[ks % 4] = w1v[((ks + 4) * 2 + 1) * 64 + lane];
            }
        }
        // epi: bn1+relu, boundary zeros, split -> c1 slab
#pragma unroll
        for (int reg = 0; reg < 16; ++reg) {
            const int rl = frag * 32 + (reg & 3) + 8 * (reg >> 2) + 4 * lh;
            if (rl < 66) {
                const int tabs = t0 - 1 + rl;
                float v = am[reg] + cx[reg] * (1.0f / 4096.0f);
                v = (tabs >= 0 && tabs < T_LEN) ? fmaxf(v * s1 + b1, 0.0f) : 0.0f;
                unsigned short h_, lo_; split2h(v, h_, lo_);
                const int ui = (((l31 >> 3) ^ (rl & 3)) * 8) + (l31 & 7);
                sm.c1h[rl][ui] = h_;
                sm.c1l[rl][ui] = lo_;
            }
        }
    }
    __syncthreads();   // B2

    if (wv < 2) {
        // ---- conv2: m-frag = wv (outputs t0 + wv*32 .. +31) ----
        const int mf = wv;
        const float s2 = (l31 < 16) ? sb[64 + l31] : 0.0f;
        const float b2 = (l31 < 16) ? sb[80 + l31] : 0.0f;
        const f16x8* w2v = reinterpret_cast<const f16x8*>(w2f);
        f16x8 w2hv[6], w2lv[6];
#pragma unroll
        for (int p = 0; p < 6; ++p) {
            w2hv[p] = w2v[(p * 2 + 0) * 64 + lane];
            w2lv[p] = w2v[(p * 2 + 1) * 64 + lane];
        }
        f32x16 am, cx;
#pragma unroll
        for (int q = 0; q < 16; ++q) { am[q] = 0.f; cx[q] = 0.f; }
#pragma unroll
        for (int ks = 0; ks < 6; ++ks) {
            const int kb = ks * 16 + lh * 8;
            const int sidx = mf * 32 + l31 + (kb >> 5);          // 0..65
            const int off = ((((kb & 31) >> 3) ^ (sidx & 3)) * 8);
            f16x8 ah = *reinterpret_cast<const f16x8*>(&sm.c1h[sidx][off]);
            f16x8 al = *reinterpret_cast<const f16x8*>(&sm.c1l[sidx][off]);
            am = MFMA32(ah, w2hv[ks], am);
            cx = MFMA32(ah, w2lv[ks], cx);
            cx = MFMA32(al, w2hv[ks], cx);
        }
        if (l31 < 16) {
#pragma unroll
            for (int g = 0; g < 4; ++g) {
                const int t = t0 + mf * 32 + 8 * g + 4 * lh;
                float4 ov;
                ov.x = fmaxf((am[g*4+0] + cx[g*4+0] * (1.0f/4096.0f)) * s2 + b2, 0.0f);
                ov.y = fmaxf((am[g*4+1] + cx[g*4+1] * (1.0f/4096.0f)) * s2 + b2, 0.0f);
                ov.z = fmaxf((am[g*4+2] + cx[g*4+2] * (1.0f/4096.0f)) * s2 + b2, 0.0f);
                ov.w = fmaxf((am[g*4+3] + cx[g*4+3] * (1.0f/4096.0f)) * s2 + b2, 0.0f);
                *reinterpret_cast<float4*>(erow + (size_t)l31 * T_LEN + t) = ov;
            }
        }
    }
}

// ---------------------------------------------------------------------------
// Scan kernel (primary): pre-gated. Thread = (row, h), fully independent —
// no in-loop barriers, no gate compute. Prefetch g+e one chunk ahead.
// ---------------------------------------------------------------------------
__global__ __launch_bounds__(256) void geo_alif_scan_pg(
    const float* __restrict__ e_ws, const float* __restrict__ g_ws,
    const float* __restrict__ gam,
    const float* __restrict__ fc1W, const float* __restrict__ fc1b,
    const float* __restrict__ fc2W, const float* __restrict__ fc2b,
    float* __restrict__ out)
{
    __shared__ float dp[16][160];
    __shared__ float h1s[16][64];

    const int tid = threadIdx.x;
    const int r = tid >> 4, h = tid & 15;
    const int b = blockIdx.x * 16 + r;
    const float* ep = e_ws + ((size_t)b * 16 + h) * T_LEN;
    const float* gp = g_ws + ((size_t)b * 16 + h) * T_LEN;
    const float gmv = gam[h];

    float mem = 0.f, eta = 0.f, li = 0.f, prev = 0.f, acc = 0.f;

    float4 ce[4], cg[4];
#pragma unroll
    for (int q = 0; q < 4; ++q) {
        ce[q] = *reinterpret_cast<const float4*>(ep + q * 4);
        cg[q] = *reinterpret_cast<const float4*>(gp + q * 4);
    }

    for (int c = 0; c < 20; ++c) {
        float4 ne[4], ng[4];
        if (c < 19) {
#pragma unroll
            for (int q = 0; q < 4; ++q) {
                ne[q] = *reinterpret_cast<const float4*>(ep + (c + 1) * 16 + q * 4);
                ng[q] = *reinterpret_cast<const float4*>(gp + (c + 1) * 16 + q * 4);
            }
        }
        float evs[16] = {ce[0].x, ce[0].y, ce[0].z, ce[0].w, ce[1].x, ce[1].y, ce[1].z, ce[1].w,
                         ce[2].x, ce[2].y, ce[2].z, ce[2].w, ce[3].x, ce[3].y, ce[3].z, ce[3].w};
        float gvs[16] = {cg[0].x, cg[0].y, cg[0].z, cg[0].w, cg[1].x, cg[1].y, cg[1].z, cg[1].w,
                         cg[2].x, cg[2].y, cg[2].z, cg[2].w, cg[3].x, cg[3].y, cg[3].z, cg[3].w};
#pragma unroll
        for (int u = 0; u < 16; ++u) {
            const int tt = c * 16 + u;
            eta = 0.36f * eta + 0.64f * prev;
            const float th = 0.5f + 1.8f * eta - gmv * gvs[u];
            mem = 0.8f * mem + evs[u];
            const bool sp = (mem >= th);
            const float spk = sp ? 1.f : 0.f;
            prev = spk;
            mem = sp ? 0.f : mem;
            li = 0.9f * li + spk;
            acc += ((tt & 31) < 16) ? -li : li;
            if ((tt & 31) == 31) {
                dp[r][h * 10 + (tt >> 5)] = acc * 0.0625f;
                acc = 0.f;
            }
        }
#pragma unroll
        for (int q = 0; q < 4; ++q) { ce[q] = ne[q]; cg[q] = ng[q]; }
    }
    __syncthreads();

    {
        const int rr = tid >> 4, j0 = tid & 15;
        float a0 = fc1b[j0], a1 = fc1b[j0 + 16], a2 = fc1b[j0 + 32], a3 = fc1b[j0 + 48];
        for (int f = 0; f < 160; ++f) {
            const float d = dp[rr][f];
            a0 = fmaf(d, fc1W[f * 64 + j0],      a0);
            a1 = fmaf(d, fc1W[f * 64 + j0 + 16], a1);
            a2 = fmaf(d, fc1W[f * 64 + j0 + 32], a2);
            a3 = fmaf(d, fc1W[f * 64 + j0 + 48], a3);
        }
        h1s[rr][j0]      = fmaxf(a0, 0.f);
        h1s[rr][j0 + 16] = fmaxf(a1, 0.f);
        h1s[rr][j0 + 32] = fmaxf(a2, 0.f);
        h1s[rr][j0 + 48] = fmaxf(a3, 0.f);
    }
    __syncthreads();

    if (tid < 64) {
        const int rr = tid >> 2, o = tid & 3;
        float a = fc2b[o];
#pragma unroll
        for (int j = 0; j < 64; ++j) a = fmaf(h1s[rr][j], fc2W[j * 4 + o], a);
        out[((size_t)(blockIdx.x * 16 + rr)) * 4 + o] = a;
    }
}

// ---------------------------------------------------------------------------
// Scan kernel (fallback, R14 form): gate computed in-kernel. Used only if
// ws_size cannot hold g_ws.
// ---------------------------------------------------------------------------
__global__ __launch_bounds__(256) void geo_alif_scan_fb(
    const float* __restrict__ e_ws, const float* __restrict__ x_geo,
    const float* __restrict__ geoW, const float* __restrict__ geob,
    const float* __restrict__ gam,
    const float* __restrict__ fc1W, const float* __restrict__ fc1b,
    const float* __restrict__ fc2W, const float* __restrict__ fc2b,
    float* __restrict__ out)
{
    __shared__ float gW[19][16];
    __shared__ float geo_s[16][16][16];
    __shared__ float dp[16][160];
    __shared__ float h1s[16][64];

    const int tid = threadIdx.x;
    for (int i = tid; i < 288; i += 256) gW[i / 16][i & 15] = geoW[i];
    if (tid < 16) gW[18][tid] = geob[tid];
    __syncthreads();

    const int r = tid >> 4, h = tid & 15;
    const int b = blockIdx.x * 16 + r;
    const float* ep = e_ws + ((size_t)b * 16 + h) * T_LEN;
    const float gmv = gam[h];

    const int rg = tid >> 4, tl = tid & 15;
    const float* xgbase = x_geo + ((size_t)(blockIdx.x * 16 + rg) * T_LEN + tl) * 18;

    float xv[18];
    loadxg18(xv, xgbase);

    float mem = 0.f, eta = 0.f, li = 0.f, prev = 0.f, acc = 0.f;

    for (int c = 0; c < 20; ++c) {
        float nx[18];
        if (c < 19) loadxg18(nx, xgbase + (size_t)(c + 1) * 16 * 18);

        const float* ec = ep + c * 16;
        float4 ev0 = *reinterpret_cast<const float4*>(ec);
        float4 ev1 = *reinterpret_cast<const float4*>(ec + 4);
        float4 ev2 = *reinterpret_cast<const float4*>(ec + 8);
        float4 ev3 = *reinterpret_cast<const float4*>(ec + 12);

#pragma unroll
        for (int hh = 0; hh < 16; ++hh) {
            float a = gW[18][hh];
#pragma unroll
            for (int i = 0; i < 18; ++i) a = fmaf(xv[i], gW[i][hh], a);
            geo_s[rg][tl][hh] = 1.f / (1.f + expf(-a));
        }
        __syncthreads();

        float evs[16] = {ev0.x, ev0.y, ev0.z, ev0.w, ev1.x, ev1.y, ev1.z, ev1.w,
                         ev2.x, ev2.y, ev2.z, ev2.w, ev3.x, ev3.y, ev3.z, ev3.w};
#pragma unroll
        for (int u = 0; u < 16; ++u) {
            const int tt = c * 16 + u;
            const float g = geo_s[r][u][h];
            eta = 0.36f * eta + 0.64f * prev;
            const float th = 0.5f + 1.8f * eta - gmv * g;
            mem = 0.8f * mem + evs[u];
            const bool sp = (mem >= th);
            const float spk = sp ? 1.f : 0.f;
            prev = spk;
            mem = sp ? 0.f : mem;
            li = 0.9f * li + spk;
            acc += ((tt & 31) < 16) ? -li : li;
            if ((tt & 31) == 31) {
                dp[r][h * 10 + (tt >> 5)] = acc * 0.0625f;
                acc = 0.f;
            }
        }
        __syncthreads();

#pragma unroll
        for (int i = 0; i < 18; ++i) xv[i] = nx[i];
    }

    {
        const int rr = tid >> 4, j0 = tid & 15;
        float a0 = fc1b[j0], a1 = fc1b[j0 + 16], a2 = fc1b[j0 + 32], a3 = fc1b[j0 + 48];
        for (int f = 0; f < 160; ++f) {
            const float d = dp[rr][f];
            a0 = fmaf(d, fc1W[f * 64 + j0],      a0);
            a1 = fmaf(d, fc1W[f * 64 + j0 + 16], a1);
            a2 = fmaf(d, fc1W[f * 64 + j0 + 32], a2);
            a3 = fmaf(d, fc1W[f * 64 + j0 + 48], a3);
        }
        h1s[rr][j0]      = fmaxf(a0, 0.f);
        h1s[rr][j0 + 16] = fmaxf(a1, 0.f);
        h1s[rr][j0 + 32] = fmaxf(a2, 0.f);
        h1s[rr][j0 + 48] = fmaxf(a3, 0.f);
    }
    __syncthreads();

    if (tid < 64) {
        const int rr = tid >> 2, o = tid & 3;
        float a = fc2b[o];
#pragma unroll
        for (int j = 0; j < 64; ++j) a = fmaf(h1s[rr][j], fc2W[j * 4 + o], a);
        out[((size_t)(blockIdx.x * 16 + rr)) * 4 + o] = a;
    }
}

extern "C" void kernel_launch(void* const* d_in, const int* in_sizes, int n_in,
                              void* d_out, int out_size, void* d_ws, size_t ws_size,
                              hipStream_t stream) {
    (void)in_sizes; (void)n_in; (void)out_size;
    const float* x_eeg = (const float*)d_in[0];
    const float* x_geo = (const float*)d_in[1];
    const float* k1    = (const float*)d_in[2];
    const float* c1b   = (const float*)d_in[3];
    const float* bn1s  = (const float*)d_in[4];
    const float* bn1b  = (const float*)d_in[5];
    const float* bn1m  = (const float*)d_in[6];
    const float* bn1v  = (const float*)d_in[7];
    const float* k2    = (const float*)d_in[8];
    const float* c2b   = (const float*)d_in[9];
    const float* bn2s  = (const float*)d_in[10];
    const float* bn2b  = (const float*)d_in[11];
    const float* bn2m  = (const float*)d_in[12];
    const float* bn2v  = (const float*)d_in[13];
    const float* geoW  = (const float*)d_in[14];
    const float* geob  = (const float*)d_in[15];
    const float* gam   = (const float*)d_in[16];
    const float* fc1W  = (const float*)d_in[17];
    const float* fc1b  = (const float*)d_in[18];
    const float* fc2W  = (const float*)d_in[19];
    const float* fc2b  = (const float*)d_in[20];

    // workspace layout
    const size_t E_BYTES = (size_t)4096 * 16 * T_LEN * 4;   // 83,886,080
    const size_t WS_NEEDED = 65536 + 2 * E_BYTES;           // ~160.1 MB
    char* wsb = (char*)d_ws;
    unsigned short* w1f = (unsigned short*)(wsb);           // 40960 B
    unsigned short* w2f = (unsigned short*)(wsb + 40960);   // 12288 B
    float* sb           = (float*)(wsb + 53248);            // 384 B
    float* e_ws         = (float*)(wsb + 65536);            // 83.9 MB

    const bool split_gate = (ws_size >= WS_NEEDED);
    float* g_ws = split_gate ? (float*)(wsb + 65536 + E_BYTES) : nullptr;
    const int ngate = split_gate ? NGATE_BLOCKS : 0;

    geo_prep_kernel<<<1, 256, 0, stream>>>(
        k1, c1b, bn1s, bn1b, bn1m, bn1v,
        k2, c2b, bn2s, bn2b, bn2m, bn2v, w1f, w2f, sb);

    geo_alif_conv_kernel<<<ngate + 4096 * 5, 256, 0, stream>>>(
        x_eeg, w1f, w2f, sb, e_ws, x_geo, geoW, geob, g_ws, ngate);

    if (split_gate)
        geo_alif_scan_pg<<<256, 256, 0, stream>>>(
            e_ws, g_ws, gam, fc1W, fc1b, fc2W, fc2b, (float*)d_out);
    else
        geo_alif_scan_fb<<<256, 256, 0, stream>>>(
            e_ws, x_geo, geoW, geob, gam, fc1W, fc1b, fc2W, fc2b, (float*)d_out);
}

// Round 16
// 280.859 us; speedup vs baseline: 2.2970x; 2.2970x over previous
//
#include <hip/hip_runtime.h>

typedef _Float16 f16;
typedef __attribute__((ext_vector_type(8))) _Float16 f16x8;
typedef __attribute__((ext_vector_type(16))) float f32x16;

#define T_LEN 320

// ---------------------------------------------------------------------------
// f16 two-limb split with scaled low limb (RNE): v = h + l/4096, res ~2^-24|v|
// ---------------------------------------------------------------------------
__device__ __forceinline__ void split2h(float v, unsigned short &h, unsigned short &l) {
    f16 hh = (f16)v;
    f16 ll = (f16)((v - (float)hh) * 4096.0f);
    h = __builtin_bit_cast(unsigned short, hh);
    l = __builtin_bit_cast(unsigned short, ll);
}

// ---------------------------------------------------------------------------
// Prep kernel: weights -> 32x32x16 MFMA B-fragment layout (f16 limb pairs)
//   w1f: [20 ks][2 limb][64 lane][8]   w2f: [6 ks][2 limb][64 lane][8]
//   sb : s1[32] b1[32] s2[16] b2[16]
// ---------------------------------------------------------------------------
__global__ __launch_bounds__(256) void geo_prep_kernel(
    const float* __restrict__ k1, const float* __restrict__ c1b,
    const float* __restrict__ bn1s, const float* __restrict__ bn1b,
    const float* __restrict__ bn1m, const float* __restrict__ bn1v,
    const float* __restrict__ k2, const float* __restrict__ c2b,
    const float* __restrict__ bn2s, const float* __restrict__ bn2b,
    const float* __restrict__ bn2m, const float* __restrict__ bn2v,
    unsigned short* __restrict__ w1f, unsigned short* __restrict__ w2f,
    float* __restrict__ sb)
{
    const int tid = threadIdx.x;
    for (int e = tid; e < 20 * 64; e += 256) {
        const int ks = e >> 6, l = e & 63;
        const int lh = l >> 5, n = l & 31;
        for (int j = 0; j < 8; ++j) {
            const int kg = ks * 16 + lh * 8 + j;       // kg = w*64+ci
            unsigned short h, lo; split2h(k1[kg * 32 + n], h, lo);
            w1f[((ks * 2 + 0) * 64 + l) * 8 + j] = h;
            w1f[((ks * 2 + 1) * 64 + l) * 8 + j] = lo;
        }
    }
    for (int e = tid; e < 6 * 64; e += 256) {
        const int ks = e >> 6, l = e & 63;
        const int lh = l >> 5, n = l & 31;
        for (int j = 0; j < 8; ++j) {
            const int kg = ks * 16 + lh * 8 + j;       // kg = tap*32+ci2
            const float v = (n < 16) ? k2[kg * 16 + n] : 0.0f;
            unsigned short h, lo; split2h(v, h, lo);
            w2f[((ks * 2 + 0) * 64 + l) * 8 + j] = h;
            w2f[((ks * 2 + 1) * 64 + l) * 8 + j] = lo;
        }
    }
    if (tid < 32) {
        const float s1 = bn1s[tid] * (1.0f / sqrtf(bn1v[tid] + 1e-5f));
        sb[tid]      = s1;
        sb[32 + tid] = bn1b[tid] + (c1b[tid] - bn1m[tid]) * s1;
    }
    if (tid < 16) {
        const float s2 = bn2s[tid] * (1.0f / sqrtf(bn2v[tid] + 1e-5f));
        sb[64 + tid] = s2;
        sb[80 + tid] = bn2b[tid] + (c2b[tid] - bn2m[tid]) * s2;
    }
}

// ---------------------------------------------------------------------------
// Conv kernel: block = (batch row, 64-t chunk); 20480 blocks x 256 thr.
// Independent blocks, 2 barriers total, 28.5 KB LDS -> 4-5 blocks/CU.
// ---------------------------------------------------------------------------
struct ConvSmem {
    unsigned short xh[70][64], xl[70][64];   // x slab, swizzled      17.9 KB
    unsigned short c1h[66][40], c1l[66][40]; // c1 slab (pad 40)      10.6 KB
};

#define MFMA32(A, B, C) __builtin_amdgcn_mfma_f32_32x32x16_f16((A), (B), (C), 0, 0, 0)

__global__ __launch_bounds__(256, 5) void geo_alif_conv_kernel(
    const float* __restrict__ x_eeg,
    const unsigned short* __restrict__ w1f, const unsigned short* __restrict__ w2f,
    const float* __restrict__ sb, float* __restrict__ e_ws)
{
    __shared__ ConvSmem sm;
    const int tid = threadIdx.x, lane = tid & 63, wv = tid >> 6;
    const int l31 = lane & 31, lh = lane >> 5;
    const int row = blockIdx.x / 5, cc = blockIdx.x % 5;
    const int t0 = cc * 64;
    const float* xrow = x_eeg + (size_t)row * (T_LEN * 64);
    float* erow = e_ws + (size_t)row * (16 * T_LEN);

    // ---- stage x slab: 70 rows x 16 float4 groups, batched (5/thread) ----
    {
        float4 v[5];
#pragma unroll
        for (int q = 0; q < 5; ++q) {
            const int fi = tid + q * 256;
            float4 tv = {0.f, 0.f, 0.f, 0.f};
            if (fi < 1120) {
                const int s = fi >> 4;
                const int tabs = t0 - 3 + s;
                if (tabs >= 0 && tabs < T_LEN)
                    tv = *reinterpret_cast<const float4*>(xrow + (size_t)tabs * 64 + (fi & 15) * 4);
            }
            v[q] = tv;
        }
#pragma unroll
        for (int q = 0; q < 5; ++q) {
            const int fi = tid + q * 256;
            if (fi < 1120) {
                const int s = fi >> 4, cq = fi & 15;
                unsigned short h0,l0,h1,l1,h2,l2,h3,l3;
                split2h(v[q].x, h0, l0); split2h(v[q].y, h1, l1);
                split2h(v[q].z, h2, l2); split2h(v[q].w, h3, l3);
                const int off = (((cq >> 1) ^ (s & 7)) * 8) + (cq & 1) * 4;
                ushort4 hv = {h0, h1, h2, h3}, lv = {l0, l1, l2, l3};
                *reinterpret_cast<ushort4*>(&sm.xh[s][off]) = hv;
                *reinterpret_cast<ushort4*>(&sm.xl[s][off]) = lv;
            }
        }
    }
    __syncthreads();   // B1

    if (wv < 3) {
        // ---- conv1: frag = wv (output rows frag*32 .. +31; valid rl<66) ----
        const int frag = wv;
        const float s1 = sb[l31], b1 = sb[32 + l31];
        const f16x8* w1v = reinterpret_cast<const f16x8*>(w1f);
        f32x16 am, cx;
#pragma unroll
        for (int q = 0; q < 16; ++q) { am[q] = 0.f; cx[q] = 0.f; }
        f16x8 pbh[4], pbl[4], pah[3], pal[3];
#pragma unroll
        for (int p = 0; p < 4; ++p) {
            pbh[p] = w1v[(p * 2 + 0) * 64 + lane];
            pbl[p] = w1v[(p * 2 + 1) * 64 + lane];
        }
#pragma unroll
        for (int p = 0; p < 3; ++p) {
            const int kb = p * 16 + lh * 8;
            int s = frag * 32 + l31 + (kb >> 6); if (s > 69) s = 69;
            const int off = ((((kb & 63) >> 3) ^ (s & 7)) * 8);
            pah[p] = *reinterpret_cast<const f16x8*>(&sm.xh[s][off]);
            pal[p] = *reinterpret_cast<const f16x8*>(&sm.xl[s][off]);
        }
#pragma unroll
        for (int ks = 0; ks < 20; ++ks) {
            const f16x8 ah = pah[ks % 3], al = pal[ks % 3];
            const f16x8 bh = pbh[ks % 4], bl = pbl[ks % 4];
            am = MFMA32(ah, bh, am);
            cx = MFMA32(ah, bl, cx);
            cx = MFMA32(al, bh, cx);
            if (ks < 17) {
                const int kb = (ks + 3) * 16 + lh * 8;
                int s = frag * 32 + l31 + (kb >> 6); if (s > 69) s = 69;
                const int off = ((((kb & 63) >> 3) ^ (s & 7)) * 8);
                pah[ks % 3] = *reinterpret_cast<const f16x8*>(&sm.xh[s][off]);
                pal[ks % 3] = *reinterpret_cast<const f16x8*>(&sm.xl[s][off]);
            }
            if (ks < 16) {
                pbh[ks % 4] = w1v[((ks + 4) * 2 + 0) * 64 + lane];
                pbl[ks % 4] = w1v[((ks + 4) * 2 + 1) * 64 + lane];
            }
        }
        // epi: bn1+relu, boundary zeros, split -> c1 slab
#pragma unroll
        for (int reg = 0; reg < 16; ++reg) {
            const int rl = frag * 32 + (reg & 3) + 8 * (reg >> 2) + 4 * lh;
            if (rl < 66) {
                const int tabs = t0 - 1 + rl;
                float v = am[reg] + cx[reg] * (1.0f / 4096.0f);
                v = (tabs >= 0 && tabs < T_LEN) ? fmaxf(v * s1 + b1, 0.0f) : 0.0f;
                unsigned short h_, lo_; split2h(v, h_, lo_);
                const int ui = (((l31 >> 3) ^ (rl & 3)) * 8) + (l31 & 7);
                sm.c1h[rl][ui] = h_;
                sm.c1l[rl][ui] = lo_;
            }
        }
    }
    __syncthreads();   // B2

    if (wv < 2) {
        // ---- conv2: m-frag = wv (outputs t0 + wv*32 .. +31) ----
        const int mf = wv;
        const float s2 = (l31 < 16) ? sb[64 + l31] : 0.0f;
        const float b2 = (l31 < 16) ? sb[80 + l31] : 0.0f;
        const f16x8* w2v = reinterpret_cast<const f16x8*>(w2f);
        f16x8 w2hv[6], w2lv[6];
#pragma unroll
        for (int p = 0; p < 6; ++p) {
            w2hv[p] = w2v[(p * 2 + 0) * 64 + lane];
            w2lv[p] = w2v[(p * 2 + 1) * 64 + lane];
        }
        f32x16 am, cx;
#pragma unroll
        for (int q = 0; q < 16; ++q) { am[q] = 0.f; cx[q] = 0.f; }
#pragma unroll
        for (int ks = 0; ks < 6; ++ks) {
            const int kb = ks * 16 + lh * 8;
            const int sidx = mf * 32 + l31 + (kb >> 5);          // 0..65
            const int off = ((((kb & 31) >> 3) ^ (sidx & 3)) * 8);
            f16x8 ah = *reinterpret_cast<const f16x8*>(&sm.c1h[sidx][off]);
            f16x8 al = *reinterpret_cast<const f16x8*>(&sm.c1l[sidx][off]);
            am = MFMA32(ah, w2hv[ks], am);
            cx = MFMA32(ah, w2lv[ks], cx);
            cx = MFMA32(al, w2hv[ks], cx);
        }
        if (l31 < 16) {
            // float4 stores: regs (g*4 .. g*4+3) are 4 consecutive t
#pragma unroll
            for (int g = 0; g < 4; ++g) {
                const int t = t0 + mf * 32 + 8 * g + 4 * lh;
                float4 ov;
                ov.x = fmaxf((am[g*4+0] + cx[g*4+0] * (1.0f/4096.0f)) * s2 + b2, 0.0f);
                ov.y = fmaxf((am[g*4+1] + cx[g*4+1] * (1.0f/4096.0f)) * s2 + b2, 0.0f);
                ov.z = fmaxf((am[g*4+2] + cx[g*4+2] * (1.0f/4096.0f)) * s2 + b2, 0.0f);
                ov.w = fmaxf((am[g*4+3] + cx[g*4+3] * (1.0f/4096.0f)) * s2 + b2, 0.0f);
                *reinterpret_cast<float4*>(erow + (size_t)l31 * T_LEN + t) = ov;
            }
        }
    }
}

// ---------------------------------------------------------------------------
// Kernel 2: geo gate + ALIF scan + diff-pool + fc1 + fc2.
// R8-proven structure; e-row chunk loads issued at loop top so the
// gate-compute phase covers their latency.
// ---------------------------------------------------------------------------
__global__ __launch_bounds__(256) void geo_alif_scan_kernel(
    const float* __restrict__ e_ws, const float* __restrict__ x_geo,
    const float* __restrict__ geoW, const float* __restrict__ geob,
    const float* __restrict__ gam,
    const float* __restrict__ fc1W, const float* __restrict__ fc1b,
    const float* __restrict__ fc2W, const float* __restrict__ fc2b,
    float* __restrict__ out)
{
    __shared__ float gW[18][16];
    __shared__ float geo_s[16][16][16];   // [row][t_local][h]
    __shared__ float dp[16][160];
    __shared__ float h1s[16][64];

    const int tid = threadIdx.x;
    for (int i = tid; i < 288; i += 256) gW[i / 16][i & 15] = geoW[i];
    __syncthreads();

    const int r = tid >> 4, h = tid & 15;
    const int b = blockIdx.x * 16 + r;
    const float* ep = e_ws + ((size_t)b * 16 + h) * T_LEN;
    const float gmv = gam[h];

    float mem = 0.f, eta = 0.f, li = 0.f, prev = 0.f, acc = 0.f;

    for (int c = 0; c < 20; ++c) {
        // e prefetch for this chunk (covered by the gate phase below)
        const float* ec = ep + c * 16;
        float4 ev0 = *reinterpret_cast<const float4*>(ec);
        float4 ev1 = *reinterpret_cast<const float4*>(ec + 4);
        float4 ev2 = *reinterpret_cast<const float4*>(ec + 8);
        float4 ev3 = *reinterpret_cast<const float4*>(ec + 12);

        {
            const int rg = tid >> 4, tl = tid & 15;
            const int t = c * 16 + tl;
            const float* xg = x_geo + ((size_t)(blockIdx.x * 16 + rg) * T_LEN + t) * 18;
            float xv[18];
#pragma unroll
            for (int i = 0; i < 18; ++i) xv[i] = xg[i];
#pragma unroll
            for (int hh = 0; hh < 16; ++hh) {
                float a = geob[hh];
#pragma unroll
                for (int i = 0; i < 18; ++i) a = fmaf(xv[i], gW[i][hh], a);
                geo_s[rg][tl][hh] = 1.f / (1.f + expf(-a));
            }
        }
        __syncthreads();

        float evs[16] = {ev0.x, ev0.y, ev0.z, ev0.w, ev1.x, ev1.y, ev1.z, ev1.w,
                         ev2.x, ev2.y, ev2.z, ev2.w, ev3.x, ev3.y, ev3.z, ev3.w};
#pragma unroll
        for (int u = 0; u < 16; ++u) {
            const int tt = c * 16 + u;
            const float g = geo_s[r][u][h];
            eta = 0.36f * eta + 0.64f * prev;
            const float th = 0.5f + 1.8f * eta - gmv * g;
            mem = 0.8f * mem + evs[u];
            const bool sp = (mem >= th);
            const float spk = sp ? 1.f : 0.f;
            prev = spk;
            mem = sp ? 0.f : mem;
            li = 0.9f * li + spk;
            acc += ((tt & 31) < 16) ? -li : li;
            if ((tt & 31) == 31) {
                dp[r][h * 10 + (tt >> 5)] = acc * 0.0625f;
                acc = 0.f;
            }
        }
        __syncthreads();
    }

    {
        const int rr = tid >> 4, j0 = tid & 15;
        float a0 = fc1b[j0], a1 = fc1b[j0 + 16], a2 = fc1b[j0 + 32], a3 = fc1b[j0 + 48];
        for (int f = 0; f < 160; ++f) {
            const float d = dp[rr][f];
            a0 = fmaf(d, fc1W[f * 64 + j0],      a0);
            a1 = fmaf(d, fc1W[f * 64 + j0 + 16], a1);
            a2 = fmaf(d, fc1W[f * 64 + j0 + 32], a2);
            a3 = fmaf(d, fc1W[f * 64 + j0 + 48], a3);
        }
        h1s[rr][j0]      = fmaxf(a0, 0.f);
        h1s[rr][j0 + 16] = fmaxf(a1, 0.f);
        h1s[rr][j0 + 32] = fmaxf(a2, 0.f);
        h1s[rr][j0 + 48] = fmaxf(a3, 0.f);
    }
    __syncthreads();

    if (tid < 64) {
        const int rr = tid >> 2, o = tid & 3;
        float a = fc2b[o];
#pragma unroll
        for (int j = 0; j < 64; ++j) a = fmaf(h1s[rr][j], fc2W[j * 4 + o], a);
        out[((size_t)(blockIdx.x * 16 + rr)) * 4 + o] = a;
    }
}

extern "C" void kernel_launch(void* const* d_in, const int* in_sizes, int n_in,
                              void* d_out, int out_size, void* d_ws, size_t ws_size,
                              hipStream_t stream) {
    (void)in_sizes; (void)n_in; (void)out_size; (void)ws_size;
    const float* x_eeg = (const float*)d_in[0];
    const float* x_geo = (const float*)d_in[1];
    const float* k1    = (const float*)d_in[2];
    const float* c1b   = (const float*)d_in[3];
    const float* bn1s  = (const float*)d_in[4];
    const float* bn1b  = (const float*)d_in[5];
    const float* bn1m  = (const float*)d_in[6];
    const float* bn1v  = (const float*)d_in[7];
    const float* k2    = (const float*)d_in[8];
    const float* c2b   = (const float*)d_in[9];
    const float* bn2s  = (const float*)d_in[10];
    const float* bn2b  = (const float*)d_in[11];
    const float* bn2m  = (const float*)d_in[12];
    const float* bn2v  = (const float*)d_in[13];
    const float* geoW  = (const float*)d_in[14];
    const float* geob  = (const float*)d_in[15];
    const float* gam   = (const float*)d_in[16];
    const float* fc1W  = (const float*)d_in[17];
    const float* fc1b  = (const float*)d_in[18];
    const float* fc2W  = (const float*)d_in[19];
    const float* fc2b  = (const float*)d_in[20];

    // workspace layout
    char* wsb = (char*)d_ws;
    unsigned short* w1f = (unsigned short*)(wsb);          // 40960 B
    unsigned short* w2f = (unsigned short*)(wsb + 40960);  // 12288 B
    float* sb           = (float*)(wsb + 53248);           // 384 B
    float* e_ws         = (float*)(wsb + 65536);           // 83.9 MB

    geo_prep_kernel<<<1, 256, 0, stream>>>(
        k1, c1b, bn1s, bn1b, bn1m, bn1v,
        k2, c2b, bn2s, bn2b, bn2m, bn2v, w1f, w2f, sb);

    geo_alif_conv_kernel<<<4096 * 5, 256, 0, stream>>>(x_eeg, w1f, w2f, sb, e_ws);

    geo_alif_scan_kernel<<<256, 256, 0, stream>>>(
        e_ws, x_geo, geoW, geob, gam, fc1W, fc1b, fc2W, fc2b, (float*)d_out);
}

// Round 18
// 266.360 us; speedup vs baseline: 2.4220x; 1.0544x over previous
//
#include <hip/hip_runtime.h>

typedef _Float16 f16;
typedef __attribute__((ext_vector_type(8))) _Float16 f16x8;
typedef __attribute__((ext_vector_type(16))) float f32x16;

#define T_LEN 320

// ---------------------------------------------------------------------------
// f16 two-limb split with scaled low limb (RNE): v = h + l/4096, res ~2^-24|v|
// ---------------------------------------------------------------------------
__device__ __forceinline__ void split2h(float v, unsigned short &h, unsigned short &l) {
    f16 hh = (f16)v;
    f16 ll = (f16)((v - (float)hh) * 4096.0f);
    h = __builtin_bit_cast(unsigned short, hh);
    l = __builtin_bit_cast(unsigned short, ll);
}

// ---------------------------------------------------------------------------
// Prep kernel: weights -> 32x32x16 MFMA B-fragment layout (f16 limb pairs)
//   w1f: [20 ks][2 limb][64 lane][8]   w2f: [6 ks][2 limb][64 lane][8]
//   sb : s1[32] b1[32] s2[16] b2[16]
// ---------------------------------------------------------------------------
__global__ __launch_bounds__(256) void geo_prep_kernel(
    const float* __restrict__ k1, const float* __restrict__ c1b,
    const float* __restrict__ bn1s, const float* __restrict__ bn1b,
    const float* __restrict__ bn1m, const float* __restrict__ bn1v,
    const float* __restrict__ k2, const float* __restrict__ c2b,
    const float* __restrict__ bn2s, const float* __restrict__ bn2b,
    const float* __restrict__ bn2m, const float* __restrict__ bn2v,
    unsigned short* __restrict__ w1f, unsigned short* __restrict__ w2f,
    float* __restrict__ sb)
{
    const int tid = threadIdx.x;
    for (int e = tid; e < 20 * 64; e += 256) {
        const int ks = e >> 6, l = e & 63;
        const int lh = l >> 5, n = l & 31;
        for (int j = 0; j < 8; ++j) {
            const int kg = ks * 16 + lh * 8 + j;       // kg = w*64+ci
            unsigned short h, lo; split2h(k1[kg * 32 + n], h, lo);
            w1f[((ks * 2 + 0) * 64 + l) * 8 + j] = h;
            w1f[((ks * 2 + 1) * 64 + l) * 8 + j] = lo;
        }
    }
    for (int e = tid; e < 6 * 64; e += 256) {
        const int ks = e >> 6, l = e & 63;
        const int lh = l >> 5, n = l & 31;
        for (int j = 0; j < 8; ++j) {
            const int kg = ks * 16 + lh * 8 + j;       // kg = tap*32+ci2
            const float v = (n < 16) ? k2[kg * 16 + n] : 0.0f;
            unsigned short h, lo; split2h(v, h, lo);
            w2f[((ks * 2 + 0) * 64 + l) * 8 + j] = h;
            w2f[((ks * 2 + 1) * 64 + l) * 8 + j] = lo;
        }
    }
    if (tid < 32) {
        const float s1 = bn1s[tid] * (1.0f / sqrtf(bn1v[tid] + 1e-5f));
        sb[tid]      = s1;
        sb[32 + tid] = bn1b[tid] + (c1b[tid] - bn1m[tid]) * s1;
    }
    if (tid < 16) {
        const float s2 = bn2s[tid] * (1.0f / sqrtf(bn2v[tid] + 1e-5f));
        sb[64 + tid] = s2;
        sb[80 + tid] = bn2b[tid] + (c2b[tid] - bn2m[tid]) * s2;
    }
}

// ---------------------------------------------------------------------------
// Conv kernel: block = (batch row, 80-t chunk); 16384 blocks x 256 thr.
// Chunk=80 cuts conv1 M-padding waste (96 rows for 82 valid vs 96-for-66 at
// chunk=64): MFMA/row -13%, barriers -20%, blocks -20%. Same structure, same
// per-output arithmetic (bit-identical results expected).
// LDS 34.3 KB -> 4 blocks/CU (same regime as the verified chunk-64 config).
// ---------------------------------------------------------------------------
struct ConvSmem {
    unsigned short xh[86][64], xl[86][64];   // x slab (t0-3..t0+82)  22.0 KB
    unsigned short c1h[82][40], c1l[82][40]; // c1 slab (t0-1..t0+80) 13.1 KB
};

#define MFMA32(A, B, C) __builtin_amdgcn_mfma_f32_32x32x16_f16((A), (B), (C), 0, 0, 0)

__global__ __launch_bounds__(256, 4) void geo_alif_conv_kernel(
    const float* __restrict__ x_eeg,
    const unsigned short* __restrict__ w1f, const unsigned short* __restrict__ w2f,
    const float* __restrict__ sb, float* __restrict__ e_ws)
{
    __shared__ ConvSmem sm;
    const int tid = threadIdx.x, lane = tid & 63, wv = tid >> 6;
    const int l31 = lane & 31, lh = lane >> 5;
    const int row = blockIdx.x >> 2, cc = blockIdx.x & 3;
    const int t0 = cc * 80;
    const float* xrow = x_eeg + (size_t)row * (T_LEN * 64);
    float* erow = e_ws + (size_t)row * (16 * T_LEN);

    // ---- stage x slab: 86 rows x 16 float4 groups, batched (6/thread) ----
    {
        float4 v[6];
#pragma unroll
        for (int q = 0; q < 6; ++q) {
            const int fi = tid + q * 256;
            float4 tv = {0.f, 0.f, 0.f, 0.f};
            if (fi < 1376) {
                const int s = fi >> 4;
                const int tabs = t0 - 3 + s;
                if (tabs >= 0 && tabs < T_LEN)
                    tv = *reinterpret_cast<const float4*>(xrow + (size_t)tabs * 64 + (fi & 15) * 4);
            }
            v[q] = tv;
        }
#pragma unroll
        for (int q = 0; q < 6; ++q) {
            const int fi = tid + q * 256;
            if (fi < 1376) {
                const int s = fi >> 4, cq = fi & 15;
                unsigned short h0,l0,h1,l1,h2,l2,h3,l3;
                split2h(v[q].x, h0, l0); split2h(v[q].y, h1, l1);
                split2h(v[q].z, h2, l2); split2h(v[q].w, h3, l3);
                const int off = (((cq >> 1) ^ (s & 7)) * 8) + (cq & 1) * 4;
                ushort4 hv = {h0, h1, h2, h3}, lv = {l0, l1, l2, l3};
                *reinterpret_cast<ushort4*>(&sm.xh[s][off]) = hv;
                *reinterpret_cast<ushort4*>(&sm.xl[s][off]) = lv;
            }
        }
    }
    __syncthreads();   // B1

    if (wv < 3) {
        // ---- conv1: frag = wv (output rows frag*32 .. +31; valid rl<82) ----
        const int frag = wv;
        const float s1 = sb[l31], b1 = sb[32 + l31];
        const f16x8* w1v = reinterpret_cast<const f16x8*>(w1f);
        f32x16 am, cx;
#pragma unroll
        for (int q = 0; q < 16; ++q) { am[q] = 0.f; cx[q] = 0.f; }
        f16x8 pbh[4], pbl[4], pah[3], pal[3];
#pragma unroll
        for (int p = 0; p < 4; ++p) {
            pbh[p] = w1v[(p * 2 + 0) * 64 + lane];
            pbl[p] = w1v[(p * 2 + 1) * 64 + lane];
        }
#pragma unroll
        for (int p = 0; p < 3; ++p) {
            const int kb = p * 16 + lh * 8;
            int s = frag * 32 + l31 + (kb >> 6); if (s > 85) s = 85;
            const int off = ((((kb & 63) >> 3) ^ (s & 7)) * 8);
            pah[p] = *reinterpret_cast<const f16x8*>(&sm.xh[s][off]);
            pal[p] = *reinterpret_cast<const f16x8*>(&sm.xl[s][off]);
        }
#pragma unroll
        for (int ks = 0; ks < 20; ++ks) {
            const f16x8 ah = pah[ks % 3], al = pal[ks % 3];
            const f16x8 bh = pbh[ks % 4], bl = pbl[ks % 4];
            am = MFMA32(ah, bh, am);
            cx = MFMA32(ah, bl, cx);
            cx = MFMA32(al, bh, cx);
            if (ks < 17) {
                const int kb = (ks + 3) * 16 + lh * 8;
                int s = frag * 32 + l31 + (kb >> 6); if (s > 85) s = 85;
                const int off = ((((kb & 63) >> 3) ^ (s & 7)) * 8);
                pah[ks % 3] = *reinterpret_cast<const f16x8*>(&sm.xh[s][off]);
                pal[ks % 3] = *reinterpret_cast<const f16x8*>(&sm.xl[s][off]);
            }
            if (ks < 16) {
                pbh[ks % 4] = w1v[((ks + 4) * 2 + 0) * 64 + lane];
                pbl[ks % 4] = w1v[((ks + 4) * 2 + 1) * 64 + lane];
            }
        }
        // epi: bn1+relu, boundary zeros, split -> c1 slab
#pragma unroll
        for (int reg = 0; reg < 16; ++reg) {
            const int rl = frag * 32 + (reg & 3) + 8 * (reg >> 2) + 4 * lh;
            if (rl < 82) {
                const int tabs = t0 - 1 + rl;
                float v = am[reg] + cx[reg] * (1.0f / 4096.0f);
                v = (tabs >= 0 && tabs < T_LEN) ? fmaxf(v * s1 + b1, 0.0f) : 0.0f;
                unsigned short h_, lo_; split2h(v, h_, lo_);
                const int ui = (((l31 >> 3) ^ (rl & 3)) * 8) + (l31 & 7);
                sm.c1h[rl][ui] = h_;
                sm.c1l[rl][ui] = lo_;
            }
        }
    }
    __syncthreads();   // B2

    if (wv < 3) {
        // ---- conv2: m-frag = wv (outputs t0 + wv*32 .. +31; valid <80) ----
        const int mf = wv;
        const float s2 = (l31 < 16) ? sb[64 + l31] : 0.0f;
        const float b2 = (l31 < 16) ? sb[80 + l31] : 0.0f;
        const f16x8* w2v = reinterpret_cast<const f16x8*>(w2f);
        f16x8 w2hv[6], w2lv[6];
#pragma unroll
        for (int p = 0; p < 6; ++p) {
            w2hv[p] = w2v[(p * 2 + 0) * 64 + lane];
            w2lv[p] = w2v[(p * 2 + 1) * 64 + lane];
        }
        f32x16 am, cx;
#pragma unroll
        for (int q = 0; q < 16; ++q) { am[q] = 0.f; cx[q] = 0.f; }
        const int o = mf * 32 + l31;                 // A-row (output-local t)
        const int ocl = (o > 79) ? 79 : o;           // clamp invalid lanes
#pragma unroll
        for (int ks = 0; ks < 6; ++ks) {
            const int kb = ks * 16 + lh * 8;
            const int sidx = ocl + (kb >> 5);        // 0..81
            const int off = ((((kb & 31) >> 3) ^ (sidx & 3)) * 8);
            f16x8 ah = *reinterpret_cast<const f16x8*>(&sm.c1h[sidx][off]);
            f16x8 al = *reinterpret_cast<const f16x8*>(&sm.c1l[sidx][off]);
            am = MFMA32(ah, w2hv[ks], am);
            cx = MFMA32(ah, w2lv[ks], cx);
            cx = MFMA32(al, w2hv[ks], cx);
        }
        if (l31 < 16) {
            // float4 stores: regs (g*4 .. g*4+3) are 4 consecutive t
#pragma unroll
            for (int g = 0; g < 4; ++g) {
                const int trow = mf * 32 + 8 * g + 4 * lh;
                if (trow < 80) {
                    const int t = t0 + trow;
                    float4 ov;
                    ov.x = fmaxf((am[g*4+0] + cx[g*4+0] * (1.0f/4096.0f)) * s2 + b2, 0.0f);
                    ov.y = fmaxf((am[g*4+1] + cx[g*4+1] * (1.0f/4096.0f)) * s2 + b2, 0.0f);
                    ov.z = fmaxf((am[g*4+2] + cx[g*4+2] * (1.0f/4096.0f)) * s2 + b2, 0.0f);
                    ov.w = fmaxf((am[g*4+3] + cx[g*4+3] * (1.0f/4096.0f)) * s2 + b2, 0.0f);
                    *reinterpret_cast<float4*>(erow + (size_t)l31 * T_LEN + t) = ov;
                }
            }
        }
    }
}

// ---------------------------------------------------------------------------
// Kernel 2: geo gate + ALIF scan + diff-pool + fc1 + fc2 (R10/R16-verified).
// ---------------------------------------------------------------------------
__global__ __launch_bounds__(256) void geo_alif_scan_kernel(
    const float* __restrict__ e_ws, const float* __restrict__ x_geo,
    const float* __restrict__ geoW, const float* __restrict__ geob,
    const float* __restrict__ gam,
    const float* __restrict__ fc1W, const float* __restrict__ fc1b,
    const float* __restrict__ fc2W, const float* __restrict__ fc2b,
    float* __restrict__ out)
{
    __shared__ float gW[18][16];
    __shared__ float geo_s[16][16][16];   // [row][t_local][h]
    __shared__ float dp[16][160];
    __shared__ float h1s[16][64];

    const int tid = threadIdx.x;
    for (int i = tid; i < 288; i += 256) gW[i / 16][i & 15] = geoW[i];
    __syncthreads();

    const int r = tid >> 4, h = tid & 15;
    const int b = blockIdx.x * 16 + r;
    const float* ep = e_ws + ((size_t)b * 16 + h) * T_LEN;
    const float gmv = gam[h];

    float mem = 0.f, eta = 0.f, li = 0.f, prev = 0.f, acc = 0.f;

    for (int c = 0; c < 20; ++c) {
        // e prefetch for this chunk (covered by the gate phase below)
        const float* ec = ep + c * 16;
        float4 ev0 = *reinterpret_cast<const float4*>(ec);
        float4 ev1 = *reinterpret_cast<const float4*>(ec + 4);
        float4 ev2 = *reinterpret_cast<const float4*>(ec + 8);
        float4 ev3 = *reinterpret_cast<const float4*>(ec + 12);

        {
            const int rg = tid >> 4, tl = tid & 15;
            const int t = c * 16 + tl;
            const float* xg = x_geo + ((size_t)(blockIdx.x * 16 + rg) * T_LEN + t) * 18;
            float xv[18];
#pragma unroll
            for (int i = 0; i < 18; ++i) xv[i] = xg[i];
#pragma unroll
            for (int hh = 0; hh < 16; ++hh) {
                float a = geob[hh];
#pragma unroll
                for (int i = 0; i < 18; ++i) a = fmaf(xv[i], gW[i][hh], a);
                geo_s[rg][tl][hh] = 1.f / (1.f + expf(-a));
            }
        }
        __syncthreads();

        float evs[16] = {ev0.x, ev0.y, ev0.z, ev0.w, ev1.x, ev1.y, ev1.z, ev1.w,
                         ev2.x, ev2.y, ev2.z, ev2.w, ev3.x, ev3.y, ev3.z, ev3.w};
#pragma unroll
        for (int u = 0; u < 16; ++u) {
            const int tt = c * 16 + u;
            const float g = geo_s[r][u][h];
            eta = 0.36f * eta + 0.64f * prev;
            const float th = 0.5f + 1.8f * eta - gmv * g;
            mem = 0.8f * mem + evs[u];
            const bool sp = (mem >= th);
            const float spk = sp ? 1.f : 0.f;
            prev = spk;
            mem = sp ? 0.f : mem;
            li = 0.9f * li + spk;
            acc += ((tt & 31) < 16) ? -li : li;
            if ((tt & 31) == 31) {
                dp[r][h * 10 + (tt >> 5)] = acc * 0.0625f;
                acc = 0.f;
            }
        }
        __syncthreads();
    }

    {
        const int rr = tid >> 4, j0 = tid & 15;
        float a0 = fc1b[j0], a1 = fc1b[j0 + 16], a2 = fc1b[j0 + 32], a3 = fc1b[j0 + 48];
        for (int f = 0; f < 160; ++f) {
            const float d = dp[rr][f];
            a0 = fmaf(d, fc1W[f * 64 + j0],      a0);
            a1 = fmaf(d, fc1W[f * 64 + j0 + 16], a1);
            a2 = fmaf(d, fc1W[f * 64 + j0 + 32], a2);
            a3 = fmaf(d, fc1W[f * 64 + j0 + 48], a3);
        }
        h1s[rr][j0]      = fmaxf(a0, 0.f);
        h1s[rr][j0 + 16] = fmaxf(a1, 0.f);
        h1s[rr][j0 + 32] = fmaxf(a2, 0.f);
        h1s[rr][j0 + 48] = fmaxf(a3, 0.f);
    }
    __syncthreads();

    if (tid < 64) {
        const int rr = tid >> 2, o = tid & 3;
        float a = fc2b[o];
#pragma unroll
        for (int j = 0; j < 64; ++j) a = fmaf(h1s[rr][j], fc2W[j * 4 + o], a);
        out[((size_t)(blockIdx.x * 16 + rr)) * 4 + o] = a;
    }
}

extern "C" void kernel_launch(void* const* d_in, const int* in_sizes, int n_in,
                              void* d_out, int out_size, void* d_ws, size_t ws_size,
                              hipStream_t stream) {
    (void)in_sizes; (void)n_in; (void)out_size; (void)ws_size;
    const float* x_eeg = (const float*)d_in[0];
    const float* x_geo = (const float*)d_in[1];
    const float* k1    = (const float*)d_in[2];
    const float* c1b   = (const float*)d_in[3];
    const float* bn1s  = (const float*)d_in[4];
    const float* bn1b  = (const float*)d_in[5];
    const float* bn1m  = (const float*)d_in[6];
    const float* bn1v  = (const float*)d_in[7];
    const float* k2    = (const float*)d_in[8];
    const float* c2b   = (const float*)d_in[9];
    const float* bn2s  = (const float*)d_in[10];
    const float* bn2b  = (const float*)d_in[11];
    const float* bn2m  = (const float*)d_in[12];
    const float* bn2v  = (const float*)d_in[13];
    const float* geoW  = (const float*)d_in[14];
    const float* geob  = (const float*)d_in[15];
    const float* gam   = (const float*)d_in[16];
    const float* fc1W  = (const float*)d_in[17];
    const float* fc1b  = (const float*)d_in[18];
    const float* fc2W  = (const float*)d_in[19];
    const float* fc2b  = (const float*)d_in[20];

    // workspace layout
    char* wsb = (char*)d_ws;
    unsigned short* w1f = (unsigned short*)(wsb);          // 40960 B
    unsigned short* w2f = (unsigned short*)(wsb + 40960);  // 12288 B
    float* sb           = (float*)(wsb + 53248);           // 384 B
    float* e_ws         = (float*)(wsb + 65536);           // 83.9 MB

    geo_prep_kernel<<<1, 256, 0, stream>>>(
        k1, c1b, bn1s, bn1b, bn1m, bn1v,
        k2, c2b, bn2s, bn2b, bn2m, bn2v, w1f, w2f, sb);

    geo_alif_conv_kernel<<<4096 * 4, 256, 0, stream>>>(x_eeg, w1f, w2f, sb, e_ws);

    geo_alif_scan_kernel<<<256, 256, 0, stream>>>(
        e_ws, x_geo, geoW, geob, gam, fc1W, fc1b, fc2W, fc2b, (float*)d_out);
}